// Round 1
// baseline (10618.350 us; speedup 1.0000x reference)
//
#include <hip/hip_runtime.h>
#include <math.h>

#define CH 128     // PAIR_CHANNELS
#define NH 8       // N_HEADS
#define DCAT 72    // NH * (MAX_PI_LENGTH+1)
#define NIJK 200000

// ---------------- Pass 2: logits -> exp -> segment denom (atomics) ----------
// Softmax max-subtraction dropped: mathematically invariant, logits ~N(0,1).
__global__ __launch_bounds__(256) void k_logits(
    const float* __restrict__ stereo, const int* __restrict__ seg,
    const float* __restrict__ Wk, float* __restrict__ alpha,
    float* __restrict__ denom, int n) {
  __shared__ float sWt[NH][132];  // transposed W, padded (bank-conflict-free b128)
  int t = threadIdx.x;
  for (int i = t; i < NH * CH; i += 256) {
    int h = i >> 7, c = i & 127;
    sWt[h][c] = Wk[c * NH + h];
  }
  __syncthreads();
  int rr = t >> 3, h = t & 7;            // 32 row-groups x 8 heads
  int base = blockIdx.x * 64;            // 64 rows per block (2 per thread)
  int r0 = base + rr, r1 = base + rr + 32;
  int r0c = r0 < n ? r0 : n - 1;
  int r1c = r1 < n ? r1 : n - 1;
  const float4* s0 = (const float4*)(stereo + (size_t)r0c * CH);
  const float4* s1 = (const float4*)(stereo + (size_t)r1c * CH);
  const float4* wt = (const float4*)(&sWt[h][0]);
  float acc0 = 0.f, acc1 = 0.f;
#pragma unroll
  for (int c4 = 0; c4 < 32; ++c4) {
    float4 w = wt[c4];
    float4 a = s0[c4];
    float4 b = s1[c4];
    acc0 = fmaf(a.w, w.w, fmaf(a.z, w.z, fmaf(a.y, w.y, fmaf(a.x, w.x, acc0))));
    acc1 = fmaf(b.w, w.w, fmaf(b.z, w.z, fmaf(b.y, w.y, fmaf(b.x, w.x, acc1))));
  }
  if (r0 < n) {
    float e = expf(acc0);
    alpha[(size_t)r0 * NH + h] = e;
    unsafeAtomicAdd(&denom[(size_t)seg[r0] * NH + h], e);
  }
  if (r1 < n) {
    float e = expf(acc1);
    alpha[(size_t)r1 * NH + h] = e;
    unsafeAtomicAdd(&denom[(size_t)seg[r1] * NH + h], e);
  }
}

// ---------------- Pass 3: alpha /= denom[seg] --------------------------------
__global__ __launch_bounds__(256) void k_norm(
    float* __restrict__ alpha, const float* __restrict__ denom,
    const int* __restrict__ seg, int n) {
  int i = blockIdx.x * 256 + threadIdx.x;
  int total = n * NH;
  if (i < total) {
    int r = i >> 3;
    alpha[i] /= denom[(size_t)seg[r] * NH + (i & 7)];
  }
}

// ---------------- Pass 4: out0 = prop @ W_value -> x[:, 0:8] -----------------
__global__ __launch_bounds__(256) void k_value(
    const float* __restrict__ prop, const float* __restrict__ Wv,
    float* __restrict__ x, int n) {
  __shared__ float sWt[NH][132];
  int t = threadIdx.x;
  for (int i = t; i < NH * CH; i += 256) {
    int h = i >> 7, c = i & 127;
    sWt[h][c] = Wv[c * NH + h];
  }
  __syncthreads();
  int rr = t >> 3, h = t & 7;
  int base = blockIdx.x * 64;
  int r0 = base + rr, r1 = base + rr + 32;
  int r0c = r0 < n ? r0 : n - 1;
  int r1c = r1 < n ? r1 : n - 1;
  const float4* s0 = (const float4*)(prop + (size_t)r0c * CH);
  const float4* s1 = (const float4*)(prop + (size_t)r1c * CH);
  const float4* wt = (const float4*)(&sWt[h][0]);
  float acc0 = 0.f, acc1 = 0.f;
#pragma unroll
  for (int c4 = 0; c4 < 32; ++c4) {
    float4 w = wt[c4];
    float4 a = s0[c4];
    float4 b = s1[c4];
    acc0 = fmaf(a.w, w.w, fmaf(a.z, w.z, fmaf(a.y, w.y, fmaf(a.x, w.x, acc0))));
    acc1 = fmaf(b.w, w.w, fmaf(b.z, w.z, fmaf(b.y, w.y, fmaf(b.x, w.x, acc1))));
  }
  if (r0 < n) x[(size_t)r0 * DCAT + h] = acc0;
  if (r1 < n) x[(size_t)r1 * DCAT + h] = acc1;
}

// ---------------- Pass 5 (x8): x[:,(t+1)*8+h] += alpha[g3]*x[g4, t*8+h] -----
__global__ __launch_bounds__(256) void k_prop(
    const float* __restrict__ alpha, const int* __restrict__ g3,
    const int* __restrict__ g4, const int* __restrict__ g5,
    float* __restrict__ x, int n, int t) {
  int u = blockIdx.x * 256 + threadIdx.x;
  if (u >= n) return;
  int i3 = g3[u], i4 = g4[u], i5 = g5[u];
  const float4* ap = (const float4*)(alpha + (size_t)i3 * NH);
  const float4* gp = (const float4*)(x + (size_t)i4 * DCAT + t * NH);
  float4 a0 = ap[0], a1 = ap[1];
  float4 g0 = gp[0], g1 = gp[1];
  float* dst = x + (size_t)i5 * DCAT + (t + 1) * NH;
  unsafeAtomicAdd(dst + 0, a0.x * g0.x);
  unsafeAtomicAdd(dst + 1, a0.y * g0.y);
  unsafeAtomicAdd(dst + 2, a0.z * g0.z);
  unsafeAtomicAdd(dst + 3, a0.w * g0.w);
  unsafeAtomicAdd(dst + 4, a1.x * g1.x);
  unsafeAtomicAdd(dst + 5, a1.y * g1.y);
  unsafeAtomicAdd(dst + 6, a1.z * g1.z);
  unsafeAtomicAdd(dst + 7, a1.w * g1.w);
}

// ---------------- Pass 6: LN -> W1 -> GELU -> W2 -> +prop -------------------
__global__ __launch_bounds__(256) void k_mlp(
    const float* __restrict__ xg, const float* __restrict__ prop,
    const float* __restrict__ lns, const float* __restrict__ lnb,
    const float* __restrict__ W1, const float* __restrict__ b1,
    const float* __restrict__ W2, const float* __restrict__ b2,
    float* __restrict__ out, int n) {
  __shared__ float sW1[DCAT][DCAT];   // 20.7 KB
  __shared__ float sW2[DCAT][CH];     // 36.9 KB
  __shared__ float sb1[DCAT], sb2[CH], slns[DCAT], slnb[DCAT];
  __shared__ float sx[32][DCAT];      // 9.2 KB
  __shared__ float sh[32][DCAT];      // 9.2 KB
  int t = threadIdx.x;
  for (int i = t; i < DCAT * DCAT; i += 256) sW1[0][i] = W1[i];
  for (int i = t; i < DCAT * CH; i += 256) sW2[0][i] = W2[i];
  if (t < DCAT) { sb1[t] = b1[t]; slns[t] = lns[t]; slnb[t] = lnb[t]; }
  if (t < CH) sb2[t] = b2[t];
  __syncthreads();
  int r = t >> 3, jg = t & 7;   // 32 rows x 8 lane-groups
  for (int base = blockIdx.x * 32; base < n; base += gridDim.x * 32) {
    int rows = min(32, n - base);
    for (int i = t; i < rows * DCAT; i += 256) sx[0][i] = xg[(size_t)base * DCAT + i];
    __syncthreads();
    bool valid = r < rows;
    // LayerNorm (8 lanes/row, shfl reduce)
    float sum = 0.f, sq = 0.f;
    if (valid) {
#pragma unroll
      for (int m = 0; m < 9; ++m) {
        float v = sx[r][jg + 8 * m];
        sum += v; sq += v * v;
      }
    }
    sum += __shfl_xor(sum, 1); sum += __shfl_xor(sum, 2); sum += __shfl_xor(sum, 4);
    sq  += __shfl_xor(sq, 1);  sq  += __shfl_xor(sq, 2);  sq  += __shfl_xor(sq, 4);
    float mu = sum * (1.f / 72.f);
    float var = sq * (1.f / 72.f) - mu * mu;
    float rstd = rsqrtf(var + 1e-5f);
    if (valid) {
#pragma unroll
      for (int m = 0; m < 9; ++m) {
        int cc = jg + 8 * m;
        float v = sx[r][cc];
        sx[r][cc] = (v - mu) * rstd * slns[cc] + slnb[cc];
      }
    }
    // no barrier needed: each row's 8 lanes live in the same wave
    // h1 = gelu(xn @ W1 + b1)
    float acc[9];
#pragma unroll
    for (int m = 0; m < 9; ++m) acc[m] = sb1[jg + 8 * m];
    for (int k = 0; k < DCAT; ++k) {
      float xv = sx[r][k];
#pragma unroll
      for (int m = 0; m < 9; ++m) acc[m] = fmaf(xv, sW1[k][jg + 8 * m], acc[m]);
    }
    if (valid) {
#pragma unroll
      for (int m = 0; m < 9; ++m) {
        float a = acc[m];
        sh[r][jg + 8 * m] = 0.5f * a * (1.f + erff(a * 0.70710678118654752f));
      }
    }
    // out = h1 @ W2 + b2 + prop  (same-wave row dependency again)
    float acc2[16];
#pragma unroll
    for (int m = 0; m < 16; ++m) acc2[m] = sb2[jg + 8 * m];
    for (int j = 0; j < DCAT; ++j) {
      float hv = sh[r][j];
#pragma unroll
      for (int m = 0; m < 16; ++m) acc2[m] = fmaf(hv, sW2[j][jg + 8 * m], acc2[m]);
    }
    if (valid) {
      size_t ob = (size_t)(base + r) * CH;
#pragma unroll
      for (int m = 0; m < 16; ++m) {
        int cc = jg + 8 * m;
        out[ob + cc] = acc2[m] + prop[ob + cc];
      }
    }
    __syncthreads();  // protect sx/sh before next tile's staging
  }
}

extern "C" void kernel_launch(void* const* d_in, const int* in_sizes, int n_in,
                              void* d_out, int out_size, void* d_ws, size_t ws_size,
                              hipStream_t stream) {
  const float* prop   = (const float*)d_in[0];
  const float* stereo = (const float*)d_in[1];
  const int* g_jkl    = (const int*)d_in[2];
  const int* g3       = (const int*)d_in[3];
  const int* g4       = (const int*)d_in[4];
  const int* g5       = (const int*)d_in[5];
  const float* Wv     = (const float*)d_in[8];
  const float* Wk     = (const float*)d_in[9];
  const float* lns    = (const float*)d_in[10];
  const float* lnb    = (const float*)d_in[11];
  const float* W1     = (const float*)d_in[12];
  const float* b1     = (const float*)d_in[13];
  const float* W2     = (const float*)d_in[14];
  const float* b2     = (const float*)d_in[15];

  const int n_ijkl  = in_sizes[1] / CH;   // 1,000,000
  const int n_uijk  = in_sizes[0] / CH;   // 400,000
  const int n_uijkl = in_sizes[3];        // 3,000,000
  const int n_ijk   = NIJK;               // 200,000 (reference constant)

  float* alpha = (float*)d_ws;                       // [n_ijkl, 8]
  float* denom = alpha + (size_t)n_ijkl * NH;        // [n_ijk, 8]
  float* x     = denom + (size_t)n_ijk * NH;         // [n_uijk, 72]

  // zero the atomic accumulators (denom + whole x buffer) every launch
  size_t zero_bytes = ((size_t)n_ijk * NH + (size_t)n_uijk * DCAT) * sizeof(float);
  hipMemsetAsync(denom, 0, zero_bytes, stream);

  k_logits<<<(n_ijkl + 63) / 64, 256, 0, stream>>>(stereo, g_jkl, Wk, alpha, denom, n_ijkl);
  k_norm<<<(n_ijkl * NH + 255) / 256, 256, 0, stream>>>(alpha, denom, g_jkl, n_ijkl);
  k_value<<<(n_uijk + 63) / 64, 256, 0, stream>>>(prop, Wv, x, n_uijk);
  for (int t = 0; t < 8; ++t) {
    k_prop<<<(n_uijkl + 255) / 256, 256, 0, stream>>>(alpha, g3, g4, g5, x, n_uijkl, t);
  }
  k_mlp<<<2048, 256, 0, stream>>>(x, prop, lns, lnb, W1, b1, W2, b2, (float*)d_out, n_uijk);
}

// Round 2
// 2288.316 us; speedup vs baseline: 4.6402x; 4.6402x over previous
//
#include <hip/hip_runtime.h>
#include <math.h>

#define CH 128     // PAIR_CHANNELS
#define NH 8       // N_HEADS
#define DCAT 72    // NH * (MAX_PI_LENGTH+1)
#define NIJK 200000
#define SCAN_BLK 1024   // elements per scan block (256 threads x 4)

// ---------------- Pass 2: logits -> exp -> segment denom (atomics) ----------
// Softmax max-subtraction dropped: mathematically invariant, logits ~N(0,1).
__global__ __launch_bounds__(256) void k_logits(
    const float* __restrict__ stereo, const int* __restrict__ seg,
    const float* __restrict__ Wk, float* __restrict__ alpha,
    float* __restrict__ denom, int n) {
  __shared__ float sWt[NH][132];
  int t = threadIdx.x;
  for (int i = t; i < NH * CH; i += 256) {
    int h = i >> 7, c = i & 127;
    sWt[h][c] = Wk[c * NH + h];
  }
  __syncthreads();
  int rr = t >> 3, h = t & 7;
  int base = blockIdx.x * 64;
  int r0 = base + rr, r1 = base + rr + 32;
  int r0c = r0 < n ? r0 : n - 1;
  int r1c = r1 < n ? r1 : n - 1;
  const float4* s0 = (const float4*)(stereo + (size_t)r0c * CH);
  const float4* s1 = (const float4*)(stereo + (size_t)r1c * CH);
  const float4* wt = (const float4*)(&sWt[h][0]);
  float acc0 = 0.f, acc1 = 0.f;
#pragma unroll
  for (int c4 = 0; c4 < 32; ++c4) {
    float4 w = wt[c4];
    float4 a = s0[c4];
    float4 b = s1[c4];
    acc0 = fmaf(a.w, w.w, fmaf(a.z, w.z, fmaf(a.y, w.y, fmaf(a.x, w.x, acc0))));
    acc1 = fmaf(b.w, w.w, fmaf(b.z, w.z, fmaf(b.y, w.y, fmaf(b.x, w.x, acc1))));
  }
  if (r0 < n) {
    float e = expf(acc0);
    alpha[(size_t)r0 * NH + h] = e;
    unsafeAtomicAdd(&denom[(size_t)seg[r0] * NH + h], e);
  }
  if (r1 < n) {
    float e = expf(acc1);
    alpha[(size_t)r1 * NH + h] = e;
    unsafeAtomicAdd(&denom[(size_t)seg[r1] * NH + h], e);
  }
}

// ---------------- Pass 3: alpha /= denom[seg] --------------------------------
__global__ __launch_bounds__(256) void k_norm(
    float* __restrict__ alpha, const float* __restrict__ denom,
    const int* __restrict__ seg, int n) {
  int i = blockIdx.x * 256 + threadIdx.x;
  int total = n * NH;
  if (i < total) {
    int r = i >> 3;
    alpha[i] /= denom[(size_t)seg[r] * NH + (i & 7)];
  }
}

// ---------------- Pass 4: out0 = prop @ W_value -> x[:, 0:8] -----------------
__global__ __launch_bounds__(256) void k_value(
    const float* __restrict__ prop, const float* __restrict__ Wv,
    float* __restrict__ x, int n) {
  __shared__ float sWt[NH][132];
  int t = threadIdx.x;
  for (int i = t; i < NH * CH; i += 256) {
    int h = i >> 7, c = i & 127;
    sWt[h][c] = Wv[c * NH + h];
  }
  __syncthreads();
  int rr = t >> 3, h = t & 7;
  int base = blockIdx.x * 64;
  int r0 = base + rr, r1 = base + rr + 32;
  int r0c = r0 < n ? r0 : n - 1;
  int r1c = r1 < n ? r1 : n - 1;
  const float4* s0 = (const float4*)(prop + (size_t)r0c * CH);
  const float4* s1 = (const float4*)(prop + (size_t)r1c * CH);
  const float4* wt = (const float4*)(&sWt[h][0]);
  float acc0 = 0.f, acc1 = 0.f;
#pragma unroll
  for (int c4 = 0; c4 < 32; ++c4) {
    float4 w = wt[c4];
    float4 a = s0[c4];
    float4 b = s1[c4];
    acc0 = fmaf(a.w, w.w, fmaf(a.z, w.z, fmaf(a.y, w.y, fmaf(a.x, w.x, acc0))));
    acc1 = fmaf(b.w, w.w, fmaf(b.z, w.z, fmaf(b.y, w.y, fmaf(b.x, w.x, acc1))));
  }
  if (r0 < n) x[(size_t)r0 * DCAT + h] = acc0;
  if (r1 < n) x[(size_t)r1 * DCAT + h] = acc1;
}

// ---------------- CSR build: histogram -> scan -> scatter -------------------
__global__ __launch_bounds__(256) void k_hist(
    const int* __restrict__ g5, int* __restrict__ counts, int n) {
  int i = blockIdx.x * 256 + threadIdx.x;
  if (i < n) atomicAdd(&counts[g5[i]], 1);
}

// per-block exclusive scan (1024 elems/block), block totals to bsum
__global__ __launch_bounds__(256) void k_scan1(
    const int* __restrict__ counts, int* __restrict__ excl,
    int* __restrict__ bsum, int n) {
  __shared__ int s[256];
  int b = blockIdx.x, t = threadIdx.x;
  int base = b * SCAN_BLK + t * 4;
  int v0 = base + 0 < n ? counts[base + 0] : 0;
  int v1 = base + 1 < n ? counts[base + 1] : 0;
  int v2 = base + 2 < n ? counts[base + 2] : 0;
  int v3 = base + 3 < n ? counts[base + 3] : 0;
  int p0 = v0, p1 = p0 + v1, p2 = p1 + v2, sum = p2 + v3;
  s[t] = sum;
  __syncthreads();
  for (int d = 1; d < 256; d <<= 1) {
    int tv = (t >= d) ? s[t - d] : 0;
    __syncthreads();
    s[t] += tv;
    __syncthreads();
  }
  int texcl = s[t] - sum;
  if (t == 255) bsum[b] = s[255];
  if (base + 0 < n) excl[base + 0] = texcl;
  if (base + 1 < n) excl[base + 1] = texcl + p0;
  if (base + 2 < n) excl[base + 2] = texcl + p1;
  if (base + 3 < n) excl[base + 3] = texcl + p2;
}

// single-block exclusive scan of block sums (nb <= 511); bsum[nb] = total
__global__ __launch_bounds__(256) void k_scan2(int* __restrict__ bsum, int nb) {
  __shared__ int s[512];
  int t = threadIdx.x;
  for (int i = t; i < nb; i += 256) s[i] = bsum[i];
  __syncthreads();
  if (t == 0) {
    int run = 0;
    for (int i = 0; i < nb; ++i) { int c = s[i]; s[i] = run; run += c; }
    s[nb] = run;
  }
  __syncthreads();
  for (int i = t; i <= nb; i += 256) bsum[i] = s[i];
}

// add block offsets; produce rowstart + cursor copy; rowstart[n] = total
__global__ __launch_bounds__(256) void k_scan3(
    int* __restrict__ rowstart, int* __restrict__ cursor,
    const int* __restrict__ bsum, int n, int nb) {
  int i = blockIdx.x * 256 + threadIdx.x;
  if (i < n) {
    int r = rowstart[i] + bsum[i >> 10];
    rowstart[i] = r;
    cursor[i] = r;
  }
  if (i == 0) rowstart[n] = bsum[nb];
}

// scatter edges into destination-sorted order
__global__ __launch_bounds__(256) void k_scatter(
    const int* __restrict__ g3, const int* __restrict__ g4,
    const int* __restrict__ g5, int* __restrict__ cursor,
    int* __restrict__ sg3, int* __restrict__ sg4, int n) {
  int i = blockIdx.x * 256 + threadIdx.x;
  if (i >= n) return;
  int u = g5[i];
  int pos = atomicAdd(&cursor[u], 1);
  sg3[pos] = g3[i];
  sg4[pos] = g4[i];
}

// ---------------- Pass 5 (x8): atomic-free CSR SpMV -------------------------
// row u, lane = head; x[u, (t+1)*8+h] = sum_e alpha[sg3[e],h] * x[sg4[e], t*8+h]
__global__ __launch_bounds__(256) void k_spmv(
    const float* __restrict__ alpha, const int* __restrict__ rowstart,
    const int* __restrict__ sg3, const int* __restrict__ sg4,
    float* __restrict__ x, int n, int t) {
  int u = blockIdx.x * 32 + (threadIdx.x >> 3);
  int lane = threadIdx.x & 7;
  if (u >= n) return;
  int s = rowstart[u], e = rowstart[u + 1];
  int src_off = t * NH + lane;
  float acc = 0.f;
  for (int k = s; k < e; ++k) {
    int i3 = sg3[k];
    int i4 = sg4[k];
    acc = fmaf(alpha[(size_t)i3 * NH + lane], x[(size_t)i4 * DCAT + src_off], acc);
  }
  x[(size_t)u * DCAT + (t + 1) * NH + lane] = acc;
}

// ---------------- Pass 6: LN -> W1 -> GELU -> W2 -> +prop -------------------
__global__ __launch_bounds__(256) void k_mlp(
    const float* __restrict__ xg, const float* __restrict__ prop,
    const float* __restrict__ lns, const float* __restrict__ lnb,
    const float* __restrict__ W1, const float* __restrict__ b1,
    const float* __restrict__ W2, const float* __restrict__ b2,
    float* __restrict__ out, int n) {
  __shared__ float sW1[DCAT][DCAT];
  __shared__ float sW2[DCAT][CH];
  __shared__ float sb1[DCAT], sb2[CH], slns[DCAT], slnb[DCAT];
  __shared__ float sx[32][DCAT];
  __shared__ float sh[32][DCAT];
  int t = threadIdx.x;
  for (int i = t; i < DCAT * DCAT; i += 256) sW1[0][i] = W1[i];
  for (int i = t; i < DCAT * CH; i += 256) sW2[0][i] = W2[i];
  if (t < DCAT) { sb1[t] = b1[t]; slns[t] = lns[t]; slnb[t] = lnb[t]; }
  if (t < CH) sb2[t] = b2[t];
  __syncthreads();
  int r = t >> 3, jg = t & 7;
  for (int base = blockIdx.x * 32; base < n; base += gridDim.x * 32) {
    int rows = min(32, n - base);
    for (int i = t; i < rows * DCAT; i += 256) sx[0][i] = xg[(size_t)base * DCAT + i];
    __syncthreads();
    bool valid = r < rows;
    float sum = 0.f, sq = 0.f;
    if (valid) {
#pragma unroll
      for (int m = 0; m < 9; ++m) {
        float v = sx[r][jg + 8 * m];
        sum += v; sq += v * v;
      }
    }
    sum += __shfl_xor(sum, 1); sum += __shfl_xor(sum, 2); sum += __shfl_xor(sum, 4);
    sq  += __shfl_xor(sq, 1);  sq  += __shfl_xor(sq, 2);  sq  += __shfl_xor(sq, 4);
    float mu = sum * (1.f / 72.f);
    float var = sq * (1.f / 72.f) - mu * mu;
    float rstd = rsqrtf(var + 1e-5f);
    if (valid) {
#pragma unroll
      for (int m = 0; m < 9; ++m) {
        int cc = jg + 8 * m;
        float v = sx[r][cc];
        sx[r][cc] = (v - mu) * rstd * slns[cc] + slnb[cc];
      }
    }
    float acc[9];
#pragma unroll
    for (int m = 0; m < 9; ++m) acc[m] = sb1[jg + 8 * m];
    for (int k = 0; k < DCAT; ++k) {
      float xv = sx[r][k];
#pragma unroll
      for (int m = 0; m < 9; ++m) acc[m] = fmaf(xv, sW1[k][jg + 8 * m], acc[m]);
    }
    if (valid) {
#pragma unroll
      for (int m = 0; m < 9; ++m) {
        float a = acc[m];
        sh[r][jg + 8 * m] = 0.5f * a * (1.f + erff(a * 0.70710678118654752f));
      }
    }
    float acc2[16];
#pragma unroll
    for (int m = 0; m < 16; ++m) acc2[m] = sb2[jg + 8 * m];
    for (int j = 0; j < DCAT; ++j) {
      float hv = sh[r][j];
#pragma unroll
      for (int m = 0; m < 16; ++m) acc2[m] = fmaf(hv, sW2[j][jg + 8 * m], acc2[m]);
    }
    if (valid) {
      size_t ob = (size_t)(base + r) * CH;
#pragma unroll
      for (int m = 0; m < 16; ++m) {
        int cc = jg + 8 * m;
        out[ob + cc] = acc2[m] + prop[ob + cc];
      }
    }
    __syncthreads();
  }
}

extern "C" void kernel_launch(void* const* d_in, const int* in_sizes, int n_in,
                              void* d_out, int out_size, void* d_ws, size_t ws_size,
                              hipStream_t stream) {
  const float* prop   = (const float*)d_in[0];
  const float* stereo = (const float*)d_in[1];
  const int* g_jkl    = (const int*)d_in[2];
  const int* g3       = (const int*)d_in[3];
  const int* g4       = (const int*)d_in[4];
  const int* g5       = (const int*)d_in[5];
  const float* Wv     = (const float*)d_in[8];
  const float* Wk     = (const float*)d_in[9];
  const float* lns    = (const float*)d_in[10];
  const float* lnb    = (const float*)d_in[11];
  const float* W1     = (const float*)d_in[12];
  const float* b1     = (const float*)d_in[13];
  const float* W2     = (const float*)d_in[14];
  const float* b2     = (const float*)d_in[15];

  const int n_ijkl  = in_sizes[1] / CH;   // 1,000,000
  const int n_uijk  = in_sizes[0] / CH;   // 400,000
  const int n_uijkl = in_sizes[3];        // 3,000,000
  const int n_ijk   = NIJK;               // 200,000

  const int nb_scan = (n_uijk + SCAN_BLK - 1) / SCAN_BLK;  // 391

  // ws layout (floats/ints, 4B each)
  float* alpha   = (float*)d_ws;                           // [n_ijkl*8]   32 MB
  float* denom   = alpha + (size_t)n_ijkl * NH;            // [n_ijk*8]    6.4 MB
  int*   counts  = (int*)(denom + (size_t)n_ijk * NH);     // [n_uijk]     1.6 MB
  int*   rowstart= counts + n_uijk;                        // [n_uijk+1]
  int*   cursor  = rowstart + n_uijk + 1;                  // [n_uijk]
  int*   bsum    = cursor + n_uijk;                        // [nb_scan+1]
  float* x       = (float*)(bsum + nb_scan + 1);           // [n_uijk*72]  115.2 MB
  int*   sg3     = (int*)(x + (size_t)n_uijk * DCAT);      // [n_uijkl]    12 MB
  int*   sg4     = sg3 + n_uijkl;                          // [n_uijkl]    12 MB

  // zero only the atomic accumulators: denom + counts (contiguous)
  hipMemsetAsync(denom, 0, ((size_t)n_ijk * NH + n_uijk) * sizeof(float), stream);

  // CSR build (independent of alpha)
  k_hist<<<(n_uijkl + 255) / 256, 256, 0, stream>>>(g5, counts, n_uijkl);
  k_scan1<<<nb_scan, 256, 0, stream>>>(counts, rowstart, bsum, n_uijk);
  k_scan2<<<1, 256, 0, stream>>>(bsum, nb_scan);
  k_scan3<<<(n_uijk + 255) / 256, 256, 0, stream>>>(rowstart, cursor, bsum, n_uijk, nb_scan);
  k_scatter<<<(n_uijkl + 255) / 256, 256, 0, stream>>>(g3, g4, g5, cursor, sg3, sg4, n_uijkl);

  // attention weights
  k_logits<<<(n_ijkl + 63) / 64, 256, 0, stream>>>(stereo, g_jkl, Wk, alpha, denom, n_ijkl);
  k_norm<<<(n_ijkl * NH + 255) / 256, 256, 0, stream>>>(alpha, denom, g_jkl, n_ijkl);

  // x[:,0:8] and 8 propagation steps (atomic-free)
  k_value<<<(n_uijk + 63) / 64, 256, 0, stream>>>(prop, Wv, x, n_uijk);
  for (int t = 0; t < 8; ++t) {
    k_spmv<<<(n_uijk + 31) / 32, 256, 0, stream>>>(alpha, rowstart, sg3, sg4, x, n_uijk, t);
  }
  k_mlp<<<2048, 256, 0, stream>>>(x, prop, lns, lnb, W1, b1, W2, b2, (float*)d_out, n_uijk);
}

// Round 3
// 2061.262 us; speedup vs baseline: 5.1514x; 1.1102x over previous
//
#include <hip/hip_runtime.h>
#include <math.h>

#define CH 128     // PAIR_CHANNELS
#define NH 8       // N_HEADS
#define DCAT 72    // NH * (MAX_PI_LENGTH+1)
#define NIJK 200000
#define SCAN_BLK 1024   // elements per scan block (256 threads x 4)

// ---------------- Pass 2: logits -> exp -> segment denom (atomics) ----------
// Softmax max-subtraction dropped: mathematically invariant, logits ~N(0,1).
__global__ __launch_bounds__(256) void k_logits(
    const float* __restrict__ stereo, const int* __restrict__ seg,
    const float* __restrict__ Wk, float* __restrict__ alpha,
    float* __restrict__ denom, int n) {
  __shared__ float sWt[NH][132];
  int t = threadIdx.x;
  for (int i = t; i < NH * CH; i += 256) {
    int h = i >> 7, c = i & 127;
    sWt[h][c] = Wk[c * NH + h];
  }
  __syncthreads();
  int rr = t >> 3, h = t & 7;
  int base = blockIdx.x * 64;
  int r0 = base + rr, r1 = base + rr + 32;
  int r0c = r0 < n ? r0 : n - 1;
  int r1c = r1 < n ? r1 : n - 1;
  const float4* s0 = (const float4*)(stereo + (size_t)r0c * CH);
  const float4* s1 = (const float4*)(stereo + (size_t)r1c * CH);
  const float4* wt = (const float4*)(&sWt[h][0]);
  float acc0 = 0.f, acc1 = 0.f;
#pragma unroll
  for (int c4 = 0; c4 < 32; ++c4) {
    float4 w = wt[c4];
    float4 a = s0[c4];
    float4 b = s1[c4];
    acc0 = fmaf(a.w, w.w, fmaf(a.z, w.z, fmaf(a.y, w.y, fmaf(a.x, w.x, acc0))));
    acc1 = fmaf(b.w, w.w, fmaf(b.z, w.z, fmaf(b.y, w.y, fmaf(b.x, w.x, acc1))));
  }
  if (r0 < n) {
    float e = expf(acc0);
    alpha[(size_t)r0 * NH + h] = e;
    unsafeAtomicAdd(&denom[(size_t)seg[r0] * NH + h], e);
  }
  if (r1 < n) {
    float e = expf(acc1);
    alpha[(size_t)r1 * NH + h] = e;
    unsafeAtomicAdd(&denom[(size_t)seg[r1] * NH + h], e);
  }
}

// ---------------- Pass 3: alpha /= denom[seg] --------------------------------
__global__ __launch_bounds__(256) void k_norm(
    float* __restrict__ alpha, const float* __restrict__ denom,
    const int* __restrict__ seg, int n) {
  int i = blockIdx.x * 256 + threadIdx.x;
  int total = n * NH;
  if (i < total) {
    int r = i >> 3;
    alpha[i] /= denom[(size_t)seg[r] * NH + (i & 7)];
  }
}

// ---------------- Pass 4: x0 = prop @ W_value -> slice 0 ---------------------
__global__ __launch_bounds__(256) void k_value(
    const float* __restrict__ prop, const float* __restrict__ Wv,
    float* __restrict__ x0, int n) {
  __shared__ float sWt[NH][132];
  int t = threadIdx.x;
  for (int i = t; i < NH * CH; i += 256) {
    int h = i >> 7, c = i & 127;
    sWt[h][c] = Wv[c * NH + h];
  }
  __syncthreads();
  int rr = t >> 3, h = t & 7;
  int base = blockIdx.x * 64;
  int r0 = base + rr, r1 = base + rr + 32;
  int r0c = r0 < n ? r0 : n - 1;
  int r1c = r1 < n ? r1 : n - 1;
  const float4* s0 = (const float4*)(prop + (size_t)r0c * CH);
  const float4* s1 = (const float4*)(prop + (size_t)r1c * CH);
  const float4* wt = (const float4*)(&sWt[h][0]);
  float acc0 = 0.f, acc1 = 0.f;
#pragma unroll
  for (int c4 = 0; c4 < 32; ++c4) {
    float4 w = wt[c4];
    float4 a = s0[c4];
    float4 b = s1[c4];
    acc0 = fmaf(a.w, w.w, fmaf(a.z, w.z, fmaf(a.y, w.y, fmaf(a.x, w.x, acc0))));
    acc1 = fmaf(b.w, w.w, fmaf(b.z, w.z, fmaf(b.y, w.y, fmaf(b.x, w.x, acc1))));
  }
  if (r0 < n) x0[(size_t)r0 * NH + h] = acc0;
  if (r1 < n) x0[(size_t)r1 * NH + h] = acc1;
}

// ---------------- CSR build: histogram -> scan -> scatter -------------------
__global__ __launch_bounds__(256) void k_hist(
    const int* __restrict__ g5, int* __restrict__ counts, int n) {
  int i = blockIdx.x * 256 + threadIdx.x;
  if (i < n) atomicAdd(&counts[g5[i]], 1);
}

__global__ __launch_bounds__(256) void k_scan1(
    const int* __restrict__ counts, int* __restrict__ excl,
    int* __restrict__ bsum, int n) {
  __shared__ int s[256];
  int b = blockIdx.x, t = threadIdx.x;
  int base = b * SCAN_BLK + t * 4;
  int v0 = base + 0 < n ? counts[base + 0] : 0;
  int v1 = base + 1 < n ? counts[base + 1] : 0;
  int v2 = base + 2 < n ? counts[base + 2] : 0;
  int v3 = base + 3 < n ? counts[base + 3] : 0;
  int p0 = v0, p1 = p0 + v1, p2 = p1 + v2, sum = p2 + v3;
  s[t] = sum;
  __syncthreads();
  for (int d = 1; d < 256; d <<= 1) {
    int tv = (t >= d) ? s[t - d] : 0;
    __syncthreads();
    s[t] += tv;
    __syncthreads();
  }
  int texcl = s[t] - sum;
  if (t == 255) bsum[b] = s[255];
  if (base + 0 < n) excl[base + 0] = texcl;
  if (base + 1 < n) excl[base + 1] = texcl + p0;
  if (base + 2 < n) excl[base + 2] = texcl + p1;
  if (base + 3 < n) excl[base + 3] = texcl + p2;
}

__global__ __launch_bounds__(256) void k_scan2(int* __restrict__ bsum, int nb) {
  __shared__ int s[512];
  int t = threadIdx.x;
  for (int i = t; i < nb; i += 256) s[i] = bsum[i];
  __syncthreads();
  if (t == 0) {
    int run = 0;
    for (int i = 0; i < nb; ++i) { int c = s[i]; s[i] = run; run += c; }
    s[nb] = run;
  }
  __syncthreads();
  for (int i = t; i <= nb; i += 256) bsum[i] = s[i];
}

__global__ __launch_bounds__(256) void k_scan3(
    int* __restrict__ rowstart, int* __restrict__ cursor,
    const int* __restrict__ bsum, int n, int nb) {
  int i = blockIdx.x * 256 + threadIdx.x;
  if (i < n) {
    int r = rowstart[i] + bsum[i >> 10];
    rowstart[i] = r;
    cursor[i] = r;
  }
  if (i == 0) rowstart[n] = bsum[nb];
}

// scatter edges into destination-sorted order, packed (g3,g4) int2
__global__ __launch_bounds__(256) void k_scatter(
    const int* __restrict__ g3, const int* __restrict__ g4,
    const int* __restrict__ g5, int* __restrict__ cursor,
    int2* __restrict__ sidx, int n) {
  int i = blockIdx.x * 256 + threadIdx.x;
  if (i >= n) return;
  int u = g5[i];
  int pos = atomicAdd(&cursor[u], 1);
  sidx[pos] = make_int2(g3[i], g4[i]);
}

// ---------------- Pass 5 (x8): atomic-free CSR SpMV on dense slices ---------
// row u, lane = head; xdst[u*8+h] = sum_e alpha[sg3*8+h] * xsrc[sg4*8+h]
__global__ __launch_bounds__(256) void k_spmv(
    const float* __restrict__ alpha, const int* __restrict__ rowstart,
    const int2* __restrict__ sidx, const float* __restrict__ xsrc,
    float* __restrict__ xdst, int n) {
  int u = blockIdx.x * 32 + (threadIdx.x >> 3);
  int lane = threadIdx.x & 7;
  if (u >= n) return;
  int s = rowstart[u], e = rowstart[u + 1];
  float acc = 0.f;
  int k = s;
  for (; k + 1 < e; k += 2) {
    int2 eA = sidx[k];
    int2 eB = sidx[k + 1];
    float aA = alpha[(size_t)eA.x * NH + lane];
    float gA = xsrc[(size_t)eA.y * NH + lane];
    float aB = alpha[(size_t)eB.x * NH + lane];
    float gB = xsrc[(size_t)eB.y * NH + lane];
    acc = fmaf(aA, gA, acc);
    acc = fmaf(aB, gB, acc);
  }
  if (k < e) {
    int2 eA = sidx[k];
    acc = fmaf(alpha[(size_t)eA.x * NH + lane], xsrc[(size_t)eA.y * NH + lane], acc);
  }
  xdst[(size_t)u * NH + lane] = acc;
}

// ---------------- Pass 6: LN -> W1 -> GELU -> W2 -> +prop -------------------
// 64-row tile, 2 rows/thread (r and r+32) to amortize LDS W-reads.
__global__ __launch_bounds__(256) void k_mlp(
    const float* __restrict__ xs, const float* __restrict__ prop,
    const float* __restrict__ lns, const float* __restrict__ lnb,
    const float* __restrict__ W1, const float* __restrict__ b1,
    const float* __restrict__ W2, const float* __restrict__ b2,
    float* __restrict__ out, int n) {
  __shared__ float sW1[DCAT][DCAT];   // 20.7 KB
  __shared__ float sW2[DCAT][CH];     // 36.9 KB
  __shared__ float sb1[DCAT], sb2[CH], slns[DCAT], slnb[DCAT];
  __shared__ float sx[64][DCAT];      // 18.4 KB  (total ~77.4 KB -> 2 blk/CU)
  int t = threadIdx.x;
  for (int i = t; i < DCAT * DCAT; i += 256) sW1[0][i] = W1[i];
  for (int i = t; i < DCAT * CH; i += 256) sW2[0][i] = W2[i];
  if (t < DCAT) { sb1[t] = b1[t]; slns[t] = lns[t]; slnb[t] = lnb[t]; }
  if (t < CH) sb2[t] = b2[t];
  __syncthreads();
  int r = t >> 3, jg = t & 7;   // rows r and r+32
  for (int base = blockIdx.x * 64; base < n; base += gridDim.x * 64) {
    int rows = min(64, n - base);
    // stage 9 slices -> sx[row][t2*8+h], coalesced per slice
#pragma unroll
    for (int t2 = 0; t2 < 9; ++t2) {
      const float* src = xs + (size_t)t2 * n * NH + (size_t)base * NH;
      for (int i = t; i < rows * NH; i += 256)
        sx[i >> 3][t2 * NH + (i & 7)] = src[i];
    }
    __syncthreads();
    int ra = r, rb = r + 32;
    bool va = ra < rows, vb = rb < rows;
    // LayerNorm both rows (8 lanes/row, shfl reduce)
    float sumA = 0.f, sqA = 0.f, sumB = 0.f, sqB = 0.f;
#pragma unroll
    for (int m = 0; m < 9; ++m) {
      float x1 = sx[ra][jg + 8 * m];
      float x2 = sx[rb][jg + 8 * m];
      sumA += x1; sqA += x1 * x1;
      sumB += x2; sqB += x2 * x2;
    }
    sumA += __shfl_xor(sumA, 1); sumA += __shfl_xor(sumA, 2); sumA += __shfl_xor(sumA, 4);
    sqA  += __shfl_xor(sqA, 1);  sqA  += __shfl_xor(sqA, 2);  sqA  += __shfl_xor(sqA, 4);
    sumB += __shfl_xor(sumB, 1); sumB += __shfl_xor(sumB, 2); sumB += __shfl_xor(sumB, 4);
    sqB  += __shfl_xor(sqB, 1);  sqB  += __shfl_xor(sqB, 2);  sqB  += __shfl_xor(sqB, 4);
    float muA = sumA * (1.f / 72.f);
    float varA = sqA * (1.f / 72.f) - muA * muA;
    float rstdA = rsqrtf(varA + 1e-5f);
    float muB = sumB * (1.f / 72.f);
    float varB = sqB * (1.f / 72.f) - muB * muB;
    float rstdB = rsqrtf(varB + 1e-5f);
#pragma unroll
    for (int m = 0; m < 9; ++m) {
      int cc = jg + 8 * m;
      float x1 = sx[ra][cc];
      float x2 = sx[rb][cc];
      sx[ra][cc] = (x1 - muA) * rstdA * slns[cc] + slnb[cc];
      sx[rb][cc] = (x2 - muB) * rstdB * slns[cc] + slnb[cc];
    }
    // rows are wave-private (row r's 8 lanes + this thread share a wave):
    // no barrier needed through phase1/gelu/phase2.
    float accA[9], accB[9];
#pragma unroll
    for (int m = 0; m < 9; ++m) { accA[m] = sb1[jg + 8 * m]; accB[m] = accA[m]; }
    for (int k = 0; k < DCAT; ++k) {
      float xa = sx[ra][k];
      float xb = sx[rb][k];
#pragma unroll
      for (int m = 0; m < 9; ++m) {
        float w = sW1[k][jg + 8 * m];
        accA[m] = fmaf(xa, w, accA[m]);
        accB[m] = fmaf(xb, w, accB[m]);
      }
    }
#pragma unroll
    for (int m = 0; m < 9; ++m) {
      float a = accA[m], b = accB[m];
      sx[ra][jg + 8 * m] = 0.5f * a * (1.f + erff(a * 0.70710678118654752f));
      sx[rb][jg + 8 * m] = 0.5f * b * (1.f + erff(b * 0.70710678118654752f));
    }
    float acc2A[16], acc2B[16];
#pragma unroll
    for (int m = 0; m < 16; ++m) { acc2A[m] = sb2[jg + 8 * m]; acc2B[m] = acc2A[m]; }
    for (int j = 0; j < DCAT; ++j) {
      float ha = sx[ra][j];
      float hb = sx[rb][j];
#pragma unroll
      for (int m = 0; m < 16; ++m) {
        float w = sW2[j][jg + 8 * m];
        acc2A[m] = fmaf(ha, w, acc2A[m]);
        acc2B[m] = fmaf(hb, w, acc2B[m]);
      }
    }
    if (va) {
      size_t ob = (size_t)(base + ra) * CH;
#pragma unroll
      for (int m = 0; m < 16; ++m) {
        int cc = jg + 8 * m;
        out[ob + cc] = acc2A[m] + prop[ob + cc];
      }
    }
    if (vb) {
      size_t ob = (size_t)(base + rb) * CH;
#pragma unroll
      for (int m = 0; m < 16; ++m) {
        int cc = jg + 8 * m;
        out[ob + cc] = acc2B[m] + prop[ob + cc];
      }
    }
    __syncthreads();  // protect sx before next tile's staging
  }
}

extern "C" void kernel_launch(void* const* d_in, const int* in_sizes, int n_in,
                              void* d_out, int out_size, void* d_ws, size_t ws_size,
                              hipStream_t stream) {
  const float* prop   = (const float*)d_in[0];
  const float* stereo = (const float*)d_in[1];
  const int* g_jkl    = (const int*)d_in[2];
  const int* g3       = (const int*)d_in[3];
  const int* g4       = (const int*)d_in[4];
  const int* g5       = (const int*)d_in[5];
  const float* Wv     = (const float*)d_in[8];
  const float* Wk     = (const float*)d_in[9];
  const float* lns    = (const float*)d_in[10];
  const float* lnb    = (const float*)d_in[11];
  const float* W1     = (const float*)d_in[12];
  const float* b1     = (const float*)d_in[13];
  const float* W2     = (const float*)d_in[14];
  const float* b2     = (const float*)d_in[15];

  const int n_ijkl  = in_sizes[1] / CH;   // 1,000,000
  const int n_uijk  = in_sizes[0] / CH;   // 400,000
  const int n_uijkl = in_sizes[3];        // 3,000,000
  const int n_ijk   = NIJK;               // 200,000

  const int nb_scan = (n_uijk + SCAN_BLK - 1) / SCAN_BLK;  // 391

  // ws layout
  float* alpha   = (float*)d_ws;                           // [n_ijkl*8]   32 MB
  float* denom   = alpha + (size_t)n_ijkl * NH;            // [n_ijk*8]    6.4 MB
  int*   counts  = (int*)(denom + (size_t)n_ijk * NH);     // [n_uijk]
  int*   rowstart= counts + n_uijk;                        // [n_uijk+1]
  int*   cursor  = rowstart + n_uijk + 1;                  // [n_uijk]
  int*   bsum    = cursor + n_uijk;                        // [nb_scan+1]
  float* xs      = (float*)(bsum + nb_scan + 1);           // 9 x [n_uijk*8] 115.2 MB
  int2*  sidx    = (int2*)(xs + (size_t)n_uijk * DCAT);    // [n_uijkl]    24 MB

  // zero only the atomic accumulators: denom + counts (contiguous)
  hipMemsetAsync(denom, 0, ((size_t)n_ijk * NH + n_uijk) * sizeof(float), stream);

  // CSR build (independent of alpha)
  k_hist<<<(n_uijkl + 255) / 256, 256, 0, stream>>>(g5, counts, n_uijkl);
  k_scan1<<<nb_scan, 256, 0, stream>>>(counts, rowstart, bsum, n_uijk);
  k_scan2<<<1, 256, 0, stream>>>(bsum, nb_scan);
  k_scan3<<<(n_uijk + 255) / 256, 256, 0, stream>>>(rowstart, cursor, bsum, n_uijk, nb_scan);
  k_scatter<<<(n_uijkl + 255) / 256, 256, 0, stream>>>(g3, g4, g5, cursor, sidx, n_uijkl);

  // attention weights
  k_logits<<<(n_ijkl + 63) / 64, 256, 0, stream>>>(stereo, g_jkl, Wk, alpha, denom, n_ijkl);
  k_norm<<<(n_ijkl * NH + 255) / 256, 256, 0, stream>>>(alpha, denom, g_jkl, n_ijkl);

  // slice 0 and 8 propagation steps (atomic-free, dense slices)
  k_value<<<(n_uijk + 63) / 64, 256, 0, stream>>>(prop, Wv, xs, n_uijk);
  for (int t = 0; t < 8; ++t) {
    const float* xsrc = xs + (size_t)t * n_uijk * NH;
    float* xdst = xs + (size_t)(t + 1) * n_uijk * NH;
    k_spmv<<<(n_uijk + 31) / 32, 256, 0, stream>>>(alpha, rowstart, sidx, xsrc, xdst, n_uijk);
  }
  k_mlp<<<2048, 256, 0, stream>>>(xs, prop, lns, lnb, W1, b1, W2, b2, (float*)d_out, n_uijk);
}